// Round 1
// baseline (308.284 us; speedup 1.0000x reference)
//
#include <hip/hip_runtime.h>
#include <hip/hip_bf16.h>

typedef short bh8 __attribute__((ext_vector_type(8)));
typedef float f4 __attribute__((ext_vector_type(4)));
typedef unsigned short u16x8 __attribute__((ext_vector_type(8)));
typedef unsigned short u16x4 __attribute__((ext_vector_type(4)));

#define N_TOK 2048
#define BATCH 8
#define DIM   1024

// f32 -> bf16 round-to-nearest-even (finite values only)
static __device__ __forceinline__ unsigned short f2bf(float f) {
  unsigned int b = __float_as_uint(f);
  b += 0x7FFFu + ((b >> 16) & 1u);
  return (unsigned short)(b >> 16);
}

static __device__ __forceinline__ void gld16(const void* g, void* lds) {
  __builtin_amdgcn_global_load_lds(
      (const __attribute__((address_space(1))) unsigned int*)g,
      (__attribute__((address_space(3))) unsigned int*)lds, 16, 0, 0);
}

// Stage a [128 rows x 64 k] bf16 tile into LDS (linear dest, XOR-swizzled via
// pre-swizzled per-lane global source, per m173/G21).  g points at element (0,0),
// ldb = global row stride in bytes.  LDS[row*128 + (kb ^ ((row&7)<<4))] = elem(row,kb).
static __device__ __forceinline__ void stage_tile(const unsigned char* g, size_t ldb,
                                                  unsigned char* lds, int w, int l) {
  const int rgrp = l >> 3;                       // row within 8-row granule
  const int srcb = (((l & 7) ^ rgrp) << 4);      // swizzled byte offset in row
  #pragma unroll
  for (int gi = 0; gi < 4; ++gi) {
    int rb = (gi * 4 + w) * 8;                   // wave-granule base row
    gld16(g + (size_t)(rb + rgrp) * ldb + srcb, lds + (gi * 4 + w) * 1024);
  }
}

// read one 16x16x32 A/B fragment (8 consecutive k at one row), swizzle-aware
static __device__ __forceinline__ bh8 fragld(const unsigned char* lds, int row, int kbyte) {
  return *(const bh8*)(lds + row * 128 + (kbyte ^ ((row & 7) << 4)));
}

// ---------------- prep kernels ----------------

static __device__ __forceinline__ float block_reduce_sum(float v, volatile float* sb, int t) {
  #pragma unroll
  for (int o = 32; o; o >>= 1) v += __shfl_xor(v, o);
  if ((t & 63) == 0) sb[t >> 6] = v;
  __syncthreads();
  float r = sb[0] + sb[1] + sb[2] + sb[3];
  __syncthreads();
  return r;
}

// embed -> normalized bf16 wn  (one block per row)
__global__ __launch_bounds__(256) void prep_wn(const float* __restrict__ e,
                                               unsigned short* __restrict__ wn) {
  __shared__ float sb[4];
  const int n = blockIdx.x, t = threadIdx.x;
  const float4 v = *(const float4*)(e + (size_t)n * DIM + t * 4);
  float ss = v.x * v.x + v.y * v.y + v.z * v.z + v.w * v.w;
  ss = block_reduce_sum(ss, sb, t);
  const float inv = 1.0f / fmaxf(sqrtf(ss), 1e-12f);
  u16x4 pk;
  pk[0] = f2bf(v.x * inv); pk[1] = f2bf(v.y * inv);
  pk[2] = f2bf(v.z * inv); pk[3] = f2bf(v.w * inv);
  *(u16x4*)(wn + (size_t)n * DIM + t * 4) = pk;
}

// per-(m,b) row inverse norms of x
__global__ __launch_bounds__(256) void prep_xn(const float* __restrict__ x,
                                               float* __restrict__ xinv) {
  __shared__ float sb[4];
  const int r = blockIdx.x, t = threadIdx.x;   // r = m*8 + b
  const float4 v = *(const float4*)(x + (size_t)r * DIM + t * 4);
  float ss = v.x * v.x + v.y * v.y + v.z * v.z + v.w * v.w;
  ss = block_reduce_sum(ss, sb, t);
  if (t == 0) {
    const int m = r >> 3, b = r & 7;
    xinv[b * N_TOK + m] = 1.0f / fmaxf(sqrtf(ss), 1e-12f);
  }
}

// x[m][b][d] -> XT[b][d][m] bf16 (raw, un-normalized: this is V)
__global__ __launch_bounds__(256) void prep_xt(const float* __restrict__ x,
                                               unsigned short* __restrict__ XT) {
  __shared__ unsigned short tile[64][65];
  const int t = threadIdx.x;
  const int m0 = blockIdx.x * 64, d0 = blockIdx.y * 64, b = blockIdx.z;
  {
    const int ml = t >> 2, dc = (t & 3) * 16;
    const float* row = x + ((size_t)(m0 + ml) * BATCH + b) * DIM + d0 + dc;
    #pragma unroll
    for (int i = 0; i < 4; ++i) {
      float4 v = *(const float4*)(row + i * 4);
      tile[ml][dc + i * 4 + 0] = f2bf(v.x);
      tile[ml][dc + i * 4 + 1] = f2bf(v.y);
      tile[ml][dc + i * 4 + 2] = f2bf(v.z);
      tile[ml][dc + i * 4 + 3] = f2bf(v.w);
    }
  }
  __syncthreads();
  {
    const int dl = t >> 2, mc = (t & 3) * 16;
    u16x8 o0, o1;
    #pragma unroll
    for (int ii = 0; ii < 8; ++ii) {
      o0[ii] = tile[mc + ii][dl];
      o1[ii] = tile[mc + 8 + ii][dl];
    }
    unsigned short* dst = XT + ((size_t)b * DIM + d0 + dl) * (size_t)N_TOK + m0 + mc;
    *(u16x8*)dst = o0;
    *(u16x8*)(dst + 8) = o1;
  }
}

// ---------------- GEMM A: S = wn . xn^T ; P = exp(S) -> ws ; row denominators ----------------

__global__ __launch_bounds__(256, 2) void kA(const float* __restrict__ x,
    const unsigned short* __restrict__ wn, const float* __restrict__ xinv,
    unsigned short* __restrict__ Pp, float* __restrict__ pden, int Mc, int c0) {
  __shared__ __align__(16) unsigned char sA[16384];
  __shared__ __align__(16) unsigned char sB[16384];
  __shared__ float pd[128][2];

  const int t = threadIdx.x, l = t & 63, w = t >> 6;
  const int wr = w >> 1, wc = w & 1;
  const int q0 = blockIdx.x * 128;
  const int m0l = blockIdx.y * 128;
  const int b = blockIdx.z;
  const int m0g = c0 + m0l;

  f4 acc[4][4];
  #pragma unroll
  for (int i = 0; i < 4; ++i)
    #pragma unroll
    for (int j = 0; j < 4; ++j) acc[i][j] = (f4)0.0f;

  // B (xn) reg-staging assignment: thread -> (row m, 32-wide d slab)
  const int ml = t >> 1, dpart = (t & 1) * 32;
  const float xiv = xinv[b * N_TOK + m0g + ml];
  const float* xrow = x + ((size_t)(m0g + ml) * BATCH + b) * DIM;
  const unsigned char* wnb = (const unsigned char*)(wn + (size_t)q0 * DIM);

  for (int kk = 0; kk < DIM / 64; ++kk) {
    const int k0 = kk * 64;
    // A tile: wn bf16 via async global->LDS, swizzled source
    stage_tile(wnb + k0 * 2, (size_t)DIM * 2, sA, w, l);
    // B tile: raw f32 x, scaled by 1/||x|| (-> xn), converted, swizzled ds_write
    float fv[32];
    #pragma unroll
    for (int i = 0; i < 8; ++i) {
      float4 v = *(const float4*)(xrow + k0 + dpart + i * 4);
      fv[4 * i + 0] = v.x; fv[4 * i + 1] = v.y;
      fv[4 * i + 2] = v.z; fv[4 * i + 3] = v.w;
    }
    #pragma unroll
    for (int c = 0; c < 4; ++c) {
      u16x8 pk;
      #pragma unroll
      for (int ii = 0; ii < 8; ++ii) pk[ii] = f2bf(fv[c * 8 + ii] * xiv);
      const int kb = (dpart + c * 8) * 2;
      *(u16x8*)(sB + ml * 128 + (kb ^ ((ml & 7) << 4))) = pk;
    }
    __syncthreads();
    #pragma unroll
    for (int ks = 0; ks < 2; ++ks) {
      bh8 af[4], bf[4];
      #pragma unroll
      for (int i = 0; i < 4; ++i)
        af[i] = fragld(sA, wr * 64 + i * 16 + (l & 15), ks * 64 + (l >> 4) * 16);
      #pragma unroll
      for (int j = 0; j < 4; ++j)
        bf[j] = fragld(sB, wc * 64 + j * 16 + (l & 15), ks * 64 + (l >> 4) * 16);
      #pragma unroll
      for (int i = 0; i < 4; ++i)
        #pragma unroll
        for (int j = 0; j < 4; ++j)
          acc[i][j] = __builtin_amdgcn_mfma_f32_16x16x32_bf16(af[i], bf[j], acc[i][j], 0, 0, 0);
    }
    __syncthreads();
  }

  // epilogue: P = exp(S) (scores in [-1,1]; no max needed), bf16 store + row sums
  float ra[4][4];
  #pragma unroll
  for (int i = 0; i < 4; ++i)
    #pragma unroll
    for (int e = 0; e < 4; ++e) ra[i][e] = 0.0f;

  #pragma unroll
  for (int j = 0; j < 4; ++j) {
    const int cl = wc * 64 + j * 16 + (l & 15);  // local m col
    #pragma unroll
    for (int i = 0; i < 4; ++i)
      #pragma unroll
      for (int e = 0; e < 4; ++e) {
        const float p = __expf(acc[i][j][e]);
        ra[i][e] += p;
        const int row = wr * 64 + i * 16 + (l >> 4) * 4 + e;  // local q
        Pp[((size_t)b * N_TOK + q0 + row) * (size_t)Mc + m0l + cl] = f2bf(p);
      }
  }
  #pragma unroll
  for (int i = 0; i < 4; ++i)
    #pragma unroll
    for (int e = 0; e < 4; ++e) {
      float s = ra[i][e];
      s += __shfl_xor(s, 1); s += __shfl_xor(s, 2);
      s += __shfl_xor(s, 4); s += __shfl_xor(s, 8);
      if ((l & 15) == 0) pd[wr * 64 + i * 16 + (l >> 4) * 4 + e][wc] = s;
    }
  __syncthreads();
  if (t < 128)
    pden[((size_t)b * N_TOK + q0 + t) * 16 + (c0 >> 7) + blockIdx.y] = pd[t][0] + pd[t][1];
}

// ---------------- GEMM B: O += P . V  (V = XT^T), O unnormalized into d_out ----------------

template <int ACC>
__global__ __launch_bounds__(256, 2) void kB(const unsigned short* __restrict__ Pp,
    const unsigned short* __restrict__ XT, float* __restrict__ out, int Mc, int c0) {
  __shared__ __align__(16) unsigned char sA[16384];
  __shared__ __align__(16) unsigned char sB[16384];

  const int t = threadIdx.x, l = t & 63, w = t >> 6;
  const int wr = w >> 1, wc = w & 1;
  const int q0 = blockIdx.x * 128;
  const int d0 = blockIdx.y * 128;
  const int b = blockIdx.z;

  f4 acc[4][4];
  #pragma unroll
  for (int i = 0; i < 4; ++i)
    #pragma unroll
    for (int j = 0; j < 4; ++j) acc[i][j] = (f4)0.0f;

  const unsigned char* Ab = (const unsigned char*)Pp + ((size_t)b * N_TOK + q0) * (size_t)Mc * 2;
  const unsigned char* Bb = (const unsigned char*)XT + (((size_t)b * DIM + d0) * (size_t)N_TOK + c0) * 2;
  const int nk = Mc / 64;

  for (int kk = 0; kk < nk; ++kk) {
    stage_tile(Ab + kk * 128, (size_t)Mc * 2, sA, w, l);
    stage_tile(Bb + kk * 128, (size_t)N_TOK * 2, sB, w, l);
    __syncthreads();
    #pragma unroll
    for (int ks = 0; ks < 2; ++ks) {
      bh8 af[4], bf[4];
      #pragma unroll
      for (int i = 0; i < 4; ++i)
        af[i] = fragld(sA, wr * 64 + i * 16 + (l & 15), ks * 64 + (l >> 4) * 16);
      #pragma unroll
      for (int j = 0; j < 4; ++j)
        bf[j] = fragld(sB, wc * 64 + j * 16 + (l & 15), ks * 64 + (l >> 4) * 16);
      #pragma unroll
      for (int i = 0; i < 4; ++i)
        #pragma unroll
        for (int j = 0; j < 4; ++j)
          acc[i][j] = __builtin_amdgcn_mfma_f32_16x16x32_bf16(af[i], bf[j], acc[i][j], 0, 0, 0);
    }
    __syncthreads();
  }

  #pragma unroll
  for (int j = 0; j < 4; ++j) {
    const int cc = d0 + wc * 64 + j * 16 + (l & 15);
    #pragma unroll
    for (int i = 0; i < 4; ++i)
      #pragma unroll
      for (int e = 0; e < 4; ++e) {
        const int row = q0 + wr * 64 + i * 16 + (l >> 4) * 4 + e;
        const size_t oi = (size_t)row * (BATCH * DIM) + (size_t)b * DIM + cc;
        float v = acc[i][j][e];
        if (ACC) v += out[oi];
        out[oi] = v;
      }
  }
}

// ---------------- final: out = LN(O/denom + x) * gamma + beta ----------------

__global__ __launch_bounds__(256) void kLN(const float* __restrict__ x,
    const float* __restrict__ gamma, const float* __restrict__ beta,
    const float* __restrict__ pden, float* __restrict__ out) {
  __shared__ float sb[8];
  const int r = blockIdx.x;            // r = n*8 + b
  const int t = threadIdx.x;
  const int n = r >> 3, b = r & 7;

  float den = 0.0f;
  const float* pp = pden + ((size_t)b * N_TOK + n) * 16;
  #pragma unroll
  for (int i = 0; i < 16; ++i) den += pp[i];
  const float rden = 1.0f / den;

  const size_t base = (size_t)r * DIM;
  const float4 o4 = *(const float4*)(out + base + t * 4);
  const float4 x4 = *(const float4*)(x + base + t * 4);
  float y0 = o4.x * rden + x4.x;
  float y1 = o4.y * rden + x4.y;
  float y2 = o4.z * rden + x4.z;
  float y3 = o4.w * rden + x4.w;

  float s1 = y0 + y1 + y2 + y3;
  float s2 = y0 * y0 + y1 * y1 + y2 * y2 + y3 * y3;
  #pragma unroll
  for (int o = 32; o; o >>= 1) { s1 += __shfl_xor(s1, o); s2 += __shfl_xor(s2, o); }
  if ((t & 63) == 0) { sb[t >> 6] = s1; sb[4 + (t >> 6)] = s2; }
  __syncthreads();
  s1 = sb[0] + sb[1] + sb[2] + sb[3];
  s2 = sb[4] + sb[5] + sb[6] + sb[7];

  const float mean = s1 * (1.0f / DIM);
  const float var = s2 * (1.0f / DIM) - mean * mean;
  const float rstd = rsqrtf(var + 1e-5f);

  const float4 g4 = *(const float4*)(gamma + t * 4);
  const float4 b4 = *(const float4*)(beta + t * 4);
  float4 rr;
  rr.x = (y0 - mean) * rstd * g4.x + b4.x;
  rr.y = (y1 - mean) * rstd * g4.y + b4.y;
  rr.z = (y2 - mean) * rstd * g4.z + b4.z;
  rr.w = (y3 - mean) * rstd * g4.w + b4.w;
  *(float4*)(out + base + t * 4) = rr;
}

// ---------------- launch ----------------

extern "C" void kernel_launch(void* const* d_in, const int* in_sizes, int n_in,
                              void* d_out, int out_size, void* d_ws, size_t ws_size,
                              hipStream_t stream) {
  (void)in_sizes; (void)n_in; (void)out_size;
  const float* x     = (const float*)d_in[0];
  const float* embed = (const float*)d_in[1];
  const float* gamma = (const float*)d_in[2];
  const float* beta  = (const float*)d_in[3];
  float* out = (float*)d_out;

  size_t off = 0;
  char* ws = (char*)d_ws;
  auto take = [&](size_t bytes) { char* p = ws + off; off += bytes; return p; };
  unsigned short* XT  = (unsigned short*)take((size_t)BATCH * DIM * N_TOK * 2);   // 33.5 MB
  unsigned short* wnb = (unsigned short*)take((size_t)N_TOK * DIM * 2);           //  4.2 MB
  float* xinv = (float*)take((size_t)BATCH * N_TOK * 4);                          // 64 KB
  float* pden = (float*)take((size_t)BATCH * N_TOK * 16 * 4);                     //  2 MB
  const size_t fixed = off;

  int Mc = 2048;
  while (Mc > 128 && fixed + (size_t)BATCH * N_TOK * Mc * 2 > ws_size) Mc >>= 1;
  unsigned short* Pp = (unsigned short*)take((size_t)BATCH * N_TOK * Mc * 2);

  prep_wn<<<N_TOK, 256, 0, stream>>>(embed, wnb);
  prep_xn<<<N_TOK * BATCH, 256, 0, stream>>>(x, xinv);
  prep_xt<<<dim3(N_TOK / 64, DIM / 64, BATCH), 256, 0, stream>>>(x, XT);

  for (int c0 = 0; c0 < N_TOK; c0 += Mc) {
    kA<<<dim3(16, Mc / 128, BATCH), 256, 0, stream>>>(x, wnb, xinv, Pp, pden, Mc, c0);
    if (c0 == 0)
      kB<0><<<dim3(16, 8, BATCH), 256, 0, stream>>>(Pp, XT, out, Mc, c0);
    else
      kB<1><<<dim3(16, 8, BATCH), 256, 0, stream>>>(Pp, XT, out, Mc, c0);
  }
  kLN<<<N_TOK * BATCH, 256, 0, stream>>>(x, gamma, beta, pden, out);
}

// Round 2
// 218.995 us; speedup vs baseline: 1.4077x; 1.4077x over previous
//
#include <hip/hip_runtime.h>
#include <hip/hip_bf16.h>

typedef short bh8 __attribute__((ext_vector_type(8)));
typedef float f4 __attribute__((ext_vector_type(4)));
typedef unsigned short u16x8 __attribute__((ext_vector_type(8)));
typedef unsigned short u16x4 __attribute__((ext_vector_type(4)));

#define N_TOK 2048
#define BATCH 8
#define DIM   1024

// f32 -> bf16 round-to-nearest-even (finite values only)
static __device__ __forceinline__ unsigned short f2bf(float f) {
  unsigned int b = __float_as_uint(f);
  b += 0x7FFFu + ((b >> 16) & 1u);
  return (unsigned short)(b >> 16);
}

static __device__ __forceinline__ void gld16(const void* g, void* lds) {
  __builtin_amdgcn_global_load_lds(
      (const __attribute__((address_space(1))) unsigned int*)g,
      (__attribute__((address_space(3))) unsigned int*)lds, 16, 0, 0);
}

// Stage a [128 rows x 64 k] bf16 tile into LDS (linear dest, XOR-swizzled via
// pre-swizzled per-lane global source, per m173/G21).  g points at element (0,0),
// ldb = global row stride in bytes.  LDS[row*128 + (kb ^ ((row&7)<<4))] = elem(row,kb).
static __device__ __forceinline__ void stage_tile(const unsigned char* g, size_t ldb,
                                                  unsigned char* lds, int w, int l) {
  const int rgrp = l >> 3;                       // row within 8-row granule
  const int srcb = (((l & 7) ^ rgrp) << 4);      // swizzled byte offset in row
  #pragma unroll
  for (int gi = 0; gi < 4; ++gi) {
    int rb = (gi * 4 + w) * 8;                   // wave-granule base row
    gld16(g + (size_t)(rb + rgrp) * ldb + srcb, lds + (gi * 4 + w) * 1024);
  }
}

// read one 16x16x32 A/B fragment (8 consecutive k at one row), swizzle-aware
static __device__ __forceinline__ bh8 fragld(const unsigned char* lds, int row, int kbyte) {
  return *(const bh8*)(lds + row * 128 + (kbyte ^ ((row & 7) << 4)));
}

// ---------------- prep kernels ----------------

static __device__ __forceinline__ float block_reduce_sum(float v, volatile float* sb, int t) {
  #pragma unroll
  for (int o = 32; o; o >>= 1) v += __shfl_xor(v, o);
  if ((t & 63) == 0) sb[t >> 6] = v;
  __syncthreads();
  float r = sb[0] + sb[1] + sb[2] + sb[3];
  __syncthreads();
  return r;
}

// embed -> normalized bf16 wn  (one block per row)
__global__ __launch_bounds__(256) void prep_wn(const float* __restrict__ e,
                                               unsigned short* __restrict__ wn) {
  __shared__ float sb[4];
  const int n = blockIdx.x, t = threadIdx.x;
  const float4 v = *(const float4*)(e + (size_t)n * DIM + t * 4);
  float ss = v.x * v.x + v.y * v.y + v.z * v.z + v.w * v.w;
  ss = block_reduce_sum(ss, sb, t);
  const float inv = 1.0f / fmaxf(sqrtf(ss), 1e-12f);
  u16x4 pk;
  pk[0] = f2bf(v.x * inv); pk[1] = f2bf(v.y * inv);
  pk[2] = f2bf(v.z * inv); pk[3] = f2bf(v.w * inv);
  *(u16x4*)(wn + (size_t)n * DIM + t * 4) = pk;
}

// x row (m,b) -> normalized bf16 xn[b][m][d]  (one block per row)
__global__ __launch_bounds__(256) void prep_xnorm(const float* __restrict__ x,
                                                  unsigned short* __restrict__ xnb) {
  __shared__ float sb[4];
  const int r = blockIdx.x, t = threadIdx.x;   // r = m*8 + b
  const float4 v = *(const float4*)(x + (size_t)r * DIM + t * 4);
  float ss = v.x * v.x + v.y * v.y + v.z * v.z + v.w * v.w;
  ss = block_reduce_sum(ss, sb, t);
  const float inv = 1.0f / fmaxf(sqrtf(ss), 1e-12f);
  const int m = r >> 3, b = r & 7;
  u16x4 pk;
  pk[0] = f2bf(v.x * inv); pk[1] = f2bf(v.y * inv);
  pk[2] = f2bf(v.z * inv); pk[3] = f2bf(v.w * inv);
  *(u16x4*)(xnb + ((size_t)b * N_TOK + m) * DIM + t * 4) = pk;
}

// x[m][b][d] -> XT[b][d][m] bf16 (raw, un-normalized: this is V)
__global__ __launch_bounds__(256) void prep_xt(const float* __restrict__ x,
                                               unsigned short* __restrict__ XT) {
  __shared__ unsigned short tile[64][65];
  const int t = threadIdx.x;
  const int m0 = blockIdx.x * 64, d0 = blockIdx.y * 64, b = blockIdx.z;
  {
    const int ml = t >> 2, dc = (t & 3) * 16;
    const float* row = x + ((size_t)(m0 + ml) * BATCH + b) * DIM + d0 + dc;
    #pragma unroll
    for (int i = 0; i < 4; ++i) {
      float4 v = *(const float4*)(row + i * 4);
      tile[ml][dc + i * 4 + 0] = f2bf(v.x);
      tile[ml][dc + i * 4 + 1] = f2bf(v.y);
      tile[ml][dc + i * 4 + 2] = f2bf(v.z);
      tile[ml][dc + i * 4 + 3] = f2bf(v.w);
    }
  }
  __syncthreads();
  {
    const int dl = t >> 2, mc = (t & 3) * 16;
    u16x8 o0, o1;
    #pragma unroll
    for (int ii = 0; ii < 8; ++ii) {
      o0[ii] = tile[mc + ii][dl];
      o1[ii] = tile[mc + 8 + ii][dl];
    }
    unsigned short* dst = XT + ((size_t)b * DIM + d0 + dl) * (size_t)N_TOK + m0 + mc;
    *(u16x8*)dst = o0;
    *(u16x8*)(dst + 8) = o1;
  }
}

// ---------------- GEMM A: S = wn . xn^T ; P = exp(S) -> ws ; row denominators ----------------

__global__ __launch_bounds__(256, 2) void kA(
    const unsigned short* __restrict__ wn, const unsigned short* __restrict__ xnb,
    unsigned short* __restrict__ Pp, float* __restrict__ pden, int Mc, int c0) {
  __shared__ __align__(16) unsigned char sA[16384];
  __shared__ __align__(16) unsigned char sB[16384];
  __shared__ float pd[128][2];

  const int t = threadIdx.x, l = t & 63, w = t >> 6;
  const int wr = w >> 1, wc = w & 1;
  const int q0 = blockIdx.x * 128;
  const int m0l = blockIdx.y * 128;
  const int b = blockIdx.z;
  const int m0g = c0 + m0l;

  f4 acc[4][4];
  #pragma unroll
  for (int i = 0; i < 4; ++i)
    #pragma unroll
    for (int j = 0; j < 4; ++j) acc[i][j] = (f4)0.0f;

  const unsigned char* Ab = (const unsigned char*)(wn + (size_t)q0 * DIM);
  const unsigned char* Bb = (const unsigned char*)(xnb + ((size_t)b * N_TOK + m0g) * DIM);

  for (int kk = 0; kk < DIM / 64; ++kk) {
    stage_tile(Ab + kk * 128, (size_t)DIM * 2, sA, w, l);
    stage_tile(Bb + kk * 128, (size_t)DIM * 2, sB, w, l);
    __syncthreads();
    #pragma unroll
    for (int ks = 0; ks < 2; ++ks) {
      bh8 af[4], bf[4];
      #pragma unroll
      for (int i = 0; i < 4; ++i)
        af[i] = fragld(sA, wr * 64 + i * 16 + (l & 15), ks * 64 + (l >> 4) * 16);
      #pragma unroll
      for (int j = 0; j < 4; ++j)
        bf[j] = fragld(sB, wc * 64 + j * 16 + (l & 15), ks * 64 + (l >> 4) * 16);
      #pragma unroll
      for (int i = 0; i < 4; ++i)
        #pragma unroll
        for (int j = 0; j < 4; ++j)
          acc[i][j] = __builtin_amdgcn_mfma_f32_16x16x32_bf16(af[i], bf[j], acc[i][j], 0, 0, 0);
    }
    __syncthreads();
  }

  // epilogue: P = exp(S) (scores in [-1,1]; no max needed), bf16 store + row sums
  float ra[4][4];
  #pragma unroll
  for (int i = 0; i < 4; ++i)
    #pragma unroll
    for (int e = 0; e < 4; ++e) ra[i][e] = 0.0f;

  #pragma unroll
  for (int j = 0; j < 4; ++j) {
    const int cl = wc * 64 + j * 16 + (l & 15);  // local m col
    #pragma unroll
    for (int i = 0; i < 4; ++i)
      #pragma unroll
      for (int e = 0; e < 4; ++e) {
        const float p = __expf(acc[i][j][e]);
        ra[i][e] += p;
        const int row = wr * 64 + i * 16 + (l >> 4) * 4 + e;  // local q
        Pp[((size_t)b * N_TOK + q0 + row) * (size_t)Mc + m0l + cl] = f2bf(p);
      }
  }
  #pragma unroll
  for (int i = 0; i < 4; ++i)
    #pragma unroll
    for (int e = 0; e < 4; ++e) {
      float s = ra[i][e];
      s += __shfl_xor(s, 1); s += __shfl_xor(s, 2);
      s += __shfl_xor(s, 4); s += __shfl_xor(s, 8);
      if ((l & 15) == 0) pd[wr * 64 + i * 16 + (l >> 4) * 4 + e][wc] = s;
    }
  __syncthreads();
  if (t < 128)
    pden[((size_t)b * N_TOK + q0 + t) * 16 + (c0 >> 7) + blockIdx.y] = pd[t][0] + pd[t][1];
}

// ---------------- GEMM B: O += P . V  (V = XT^T); final chunk applies 1/den and +x ----------------

template <int ACC, int FINAL>
__global__ __launch_bounds__(256, 2) void kB(const unsigned short* __restrict__ Pp,
    const unsigned short* __restrict__ XT, const float* __restrict__ x,
    const float* __restrict__ pden, float* __restrict__ out, int Mc, int c0) {
  __shared__ __align__(16) unsigned char sA[16384];
  __shared__ __align__(16) unsigned char sB[16384];
  __shared__ float rden_s[128];

  const int t = threadIdx.x, l = t & 63, w = t >> 6;
  const int wr = w >> 1, wc = w & 1;
  const int q0 = blockIdx.x * 128;
  const int d0 = blockIdx.y * 128;
  const int b = blockIdx.z;

  f4 acc[4][4];
  #pragma unroll
  for (int i = 0; i < 4; ++i)
    #pragma unroll
    for (int j = 0; j < 4; ++j) acc[i][j] = (f4)0.0f;

  const unsigned char* Ab = (const unsigned char*)Pp + ((size_t)b * N_TOK + q0) * (size_t)Mc * 2;
  const unsigned char* Bb = (const unsigned char*)XT + (((size_t)b * DIM + d0) * (size_t)N_TOK + c0) * 2;
  const int nk = Mc / 64;

  for (int kk = 0; kk < nk; ++kk) {
    stage_tile(Ab + kk * 128, (size_t)Mc * 2, sA, w, l);
    stage_tile(Bb + kk * 128, (size_t)N_TOK * 2, sB, w, l);
    __syncthreads();
    #pragma unroll
    for (int ks = 0; ks < 2; ++ks) {
      bh8 af[4], bf[4];
      #pragma unroll
      for (int i = 0; i < 4; ++i)
        af[i] = fragld(sA, wr * 64 + i * 16 + (l & 15), ks * 64 + (l >> 4) * 16);
      #pragma unroll
      for (int j = 0; j < 4; ++j)
        bf[j] = fragld(sB, wc * 64 + j * 16 + (l & 15), ks * 64 + (l >> 4) * 16);
      #pragma unroll
      for (int i = 0; i < 4; ++i)
        #pragma unroll
        for (int j = 0; j < 4; ++j)
          acc[i][j] = __builtin_amdgcn_mfma_f32_16x16x32_bf16(af[i], bf[j], acc[i][j], 0, 0, 0);
    }
    __syncthreads();
  }

  if (FINAL) {
    if (t < 128) {
      const float* pp = pden + ((size_t)b * N_TOK + q0 + t) * 16;
      float s = 0.0f;
      #pragma unroll
      for (int i = 0; i < 16; ++i) s += pp[i];
      rden_s[t] = 1.0f / s;
    }
    __syncthreads();
  }

  #pragma unroll
  for (int j = 0; j < 4; ++j) {
    const int cc = d0 + wc * 64 + j * 16 + (l & 15);
    #pragma unroll
    for (int i = 0; i < 4; ++i)
      #pragma unroll
      for (int e = 0; e < 4; ++e) {
        const int rl = wr * 64 + i * 16 + (l >> 4) * 4 + e;
        const int row = q0 + rl;
        const size_t oi = (size_t)row * (BATCH * DIM) + (size_t)b * DIM + cc;
        float v = acc[i][j][e];
        if (ACC) v += out[oi];
        if (FINAL) v = v * rden_s[rl] + x[oi];
        out[oi] = v;
      }
  }
}

// ---------------- final: out = LN(y) * gamma + beta  (y already = O/den + x) ----------------

__global__ __launch_bounds__(256) void kLN(const float* __restrict__ gamma,
    const float* __restrict__ beta, float* __restrict__ out) {
  __shared__ float sb[8];
  const int r = blockIdx.x;            // r = n*8 + b
  const int t = threadIdx.x;

  const size_t base = (size_t)r * DIM;
  const float4 y4 = *(const float4*)(out + base + t * 4);
  const float y0 = y4.x, y1 = y4.y, y2 = y4.z, y3 = y4.w;

  float s1 = y0 + y1 + y2 + y3;
  float s2 = y0 * y0 + y1 * y1 + y2 * y2 + y3 * y3;
  #pragma unroll
  for (int o = 32; o; o >>= 1) { s1 += __shfl_xor(s1, o); s2 += __shfl_xor(s2, o); }
  if ((t & 63) == 0) { sb[t >> 6] = s1; sb[4 + (t >> 6)] = s2; }
  __syncthreads();
  s1 = sb[0] + sb[1] + sb[2] + sb[3];
  s2 = sb[4] + sb[5] + sb[6] + sb[7];

  const float mean = s1 * (1.0f / DIM);
  const float var = s2 * (1.0f / DIM) - mean * mean;
  const float rstd = rsqrtf(var + 1e-5f);

  const float4 g4 = *(const float4*)(gamma + t * 4);
  const float4 b4 = *(const float4*)(beta + t * 4);
  float4 rr;
  rr.x = (y0 - mean) * rstd * g4.x + b4.x;
  rr.y = (y1 - mean) * rstd * g4.y + b4.y;
  rr.z = (y2 - mean) * rstd * g4.z + b4.z;
  rr.w = (y3 - mean) * rstd * g4.w + b4.w;
  *(float4*)(out + base + t * 4) = rr;
}

// ---------------- launch ----------------

extern "C" void kernel_launch(void* const* d_in, const int* in_sizes, int n_in,
                              void* d_out, int out_size, void* d_ws, size_t ws_size,
                              hipStream_t stream) {
  (void)in_sizes; (void)n_in; (void)out_size;
  const float* x     = (const float*)d_in[0];
  const float* embed = (const float*)d_in[1];
  const float* gamma = (const float*)d_in[2];
  const float* beta  = (const float*)d_in[3];
  float* out = (float*)d_out;

  size_t off = 0;
  char* ws = (char*)d_ws;
  auto take = [&](size_t bytes) { char* p = ws + off; off += bytes; return p; };
  unsigned short* XT  = (unsigned short*)take((size_t)BATCH * DIM * N_TOK * 2);   // 33.5 MB
  unsigned short* xnb = (unsigned short*)take((size_t)BATCH * N_TOK * DIM * 2);   // 33.5 MB
  unsigned short* wnb = (unsigned short*)take((size_t)N_TOK * DIM * 2);           //  4.2 MB
  float* pden = (float*)take((size_t)BATCH * N_TOK * 16 * 4);                     //  2 MB
  const size_t fixed = off;

  int Mc = 2048;
  while (Mc > 128 && fixed + (size_t)BATCH * N_TOK * Mc * 2 > ws_size) Mc >>= 1;
  unsigned short* Pp = (unsigned short*)take((size_t)BATCH * N_TOK * Mc * 2);

  prep_wn<<<N_TOK, 256, 0, stream>>>(embed, wnb);
  prep_xnorm<<<N_TOK * BATCH, 256, 0, stream>>>(x, xnb);
  prep_xt<<<dim3(N_TOK / 64, DIM / 64, BATCH), 256, 0, stream>>>(x, XT);

  const int nchunk = N_TOK / Mc;
  for (int ci = 0; ci < nchunk; ++ci) {
    const int c0 = ci * Mc;
    kA<<<dim3(16, Mc / 128, BATCH), 256, 0, stream>>>(wnb, xnb, Pp, pden, Mc, c0);
    const bool first = (ci == 0), last = (ci == nchunk - 1);
    if (first && last)
      kB<0, 1><<<dim3(16, 8, BATCH), 256, 0, stream>>>(Pp, XT, x, pden, out, Mc, c0);
    else if (first)
      kB<0, 0><<<dim3(16, 8, BATCH), 256, 0, stream>>>(Pp, XT, x, pden, out, Mc, c0);
    else if (last)
      kB<1, 1><<<dim3(16, 8, BATCH), 256, 0, stream>>>(Pp, XT, x, pden, out, Mc, c0);
    else
      kB<1, 0><<<dim3(16, 8, BATCH), 256, 0, stream>>>(Pp, XT, x, pden, out, Mc, c0);
  }
  kLN<<<N_TOK * BATCH, 256, 0, stream>>>(gamma, beta, out);
}